// Round 9
// baseline (302.317 us; speedup 1.0000x reference)
//
#include <hip/hip_runtime.h>
#include <math.h>

#define N_NODES 50000
#define N_EDGES 500000
#define HIDDEN 128
#define HEADS 8
#define HEAD_DIM 16

typedef __attribute__((ext_vector_type(8))) short short8;     // 8 bf16 (4 VGPRs) MFMA A/B frag
typedef __attribute__((ext_vector_type(4))) float floatx4;    // MFMA C/D frag

// workspace layout, element offsets (4-byte units)
#define OFF_Q       0u           // scan scratch (pre-qkv) -> q fp32 [50000x128]
#define OFF_KV      6400000u     // kv packed bf16 pairs [50000x128] (k lo16, v hi16)
#define OFF_HHI     12800000u    // hupd_hi bf16 [50000x128]
#define OFF_HLO     16000000u    // hupd_lo bf16 [50000x128]
#define OFF_DISP    19200000u    // 150,000 floats
#define OFF_CNT     19350016u    // 50,000 ints
#define OFF_ROWPTR  19400032u    // 50,001 ints
#define OFF_CURSOR  19450048u    // 50,000 ints
#define OFF_ESD     19500064u    // 1,000,000 ints (int2 per edge: dst, dist^2 bits, CSR order)
#define OFF_WSPLIT  20500064u    // W{q,k,v,o,g1} split-bf16 frag order: 81,920 float slots
// end: 20,581,984 floats = 82.3 MB

static __device__ __forceinline__ unsigned short f2bf(float f) {
    unsigned u = __builtin_bit_cast(unsigned, f);
    unsigned r = (u + 0x7FFFu + ((u >> 16) & 1u)) >> 16;      // RNE
    return (unsigned short)r;
}
static __device__ __forceinline__ float bf2f(unsigned short s) {
    return __builtin_bit_cast(float, (unsigned)s << 16);
}

__global__ void k_zero_int(int* __restrict__ p, int n) {
    int i = blockIdx.x * 256 + threadIdx.x;
    if (i < n) p[i] = 0;
}

// repack W{q,k,v,o,g1} into split-bf16 MFMA B-fragment order:
// frag(m,kc,ct,hilo): 64 lanes x 8 bf16, lane holds B[k=kc*32+(lane>>4)*8+j][n=ct*16+(lane&15)]
__global__ void k_split_w(const float* __restrict__ Wq, const float* __restrict__ Wk,
                          const float* __restrict__ Wv, const float* __restrict__ Wo,
                          const float* __restrict__ Wg1, unsigned short* __restrict__ ws) {
    int t = blockIdx.x * 256 + threadIdx.x;          // grid exact: 5*16384
    int m = t >> 14, r = t & 16383;
    int k = r >> 7, n = r & 127;
    const float* W = (m == 0) ? Wq : (m == 1) ? Wk : (m == 2) ? Wv : (m == 3) ? Wo : Wg1;
    float x = W[k * 128 + n];
    int kc = k >> 5, kin = k & 31, quad = kin >> 3, j = kin & 7;
    int ct = n >> 4, nin = n & 15, lane = quad * 16 + nin;
    unsigned base = ((((unsigned)(m * 4 + kc) * 8 + ct) * 2) * 64 + lane) * 8 + j;
    unsigned short a = f2bf(x);
    ws[base] = a;                                    // hilo=0
    ws[base + 512] = f2bf(x - bf2f(a));              // hilo=1 (+64 lanes*8)
}

// q/k/v via split-bf16 MFMA, h split done in-register (no split_h kernel).
// 64 rows/block (rt=4), 4 waves; wave w owns col-tiles {2w,2w+1} for all 3 mats.
// q written fp32; k,v packed as bf16 pairs (k lo16, v hi16).
__global__ __launch_bounds__(256) void k_qkv_mfma(
    const float* __restrict__ h, const unsigned short* __restrict__ wsp,
    const float* __restrict__ bq, const float* __restrict__ bk, const float* __restrict__ bv,
    float* __restrict__ q, unsigned* __restrict__ kvp) {
    const int wave = threadIdx.x >> 6, lane = threadIdx.x & 63;
    const int quad = lane >> 4, l15 = lane & 15;
    const int ct0 = wave * 2;
    const int row0 = blockIdx.x * 64;

    floatx4 acc[3][2][4];                            // [mat][ctl][rt]
#pragma unroll
    for (int m = 0; m < 3; ++m)
#pragma unroll
        for (int c = 0; c < 2; ++c)
#pragma unroll
            for (int r = 0; r < 4; ++r) acc[m][c][r] = (floatx4){0.f, 0.f, 0.f, 0.f};

#pragma unroll
    for (int kc = 0; kc < 4; ++kc) {
        short8 ah[4], al[4];
#pragma unroll
        for (int rt = 0; rt < 4; ++rt) {
            int row = row0 + rt * 16 + l15;
            if (row >= N_NODES) row = N_NODES - 1;
            const float* hp = h + (size_t)row * 128 + kc * 32 + quad * 8;
            float4 f0 = *(const float4*)(hp);
            float4 f1 = *(const float4*)(hp + 4);
            float fv[8] = {f0.x, f0.y, f0.z, f0.w, f1.x, f1.y, f1.z, f1.w};
#pragma unroll
            for (int j = 0; j < 8; ++j) {
                unsigned short hi = f2bf(fv[j]);
                ah[rt][j] = (short)hi;
                al[rt][j] = (short)f2bf(fv[j] - bf2f(hi));
            }
        }
#pragma unroll
        for (int m = 0; m < 3; ++m) {
#pragma unroll
            for (int ctl = 0; ctl < 2; ++ctl) {
                unsigned fb = ((((unsigned)(m * 4 + kc) * 8 + (ct0 + ctl)) * 2) * 64 + lane) * 8;
                short8 bh = *(const short8*)(wsp + fb);
                short8 bl = *(const short8*)(wsp + fb + 512);
#pragma unroll
                for (int rt = 0; rt < 4; ++rt) {
                    acc[m][ctl][rt] = __builtin_amdgcn_mfma_f32_16x16x32_bf16(
                        ah[rt], bh, acc[m][ctl][rt], 0, 0, 0);
                    acc[m][ctl][rt] = __builtin_amdgcn_mfma_f32_16x16x32_bf16(
                        ah[rt], bl, acc[m][ctl][rt], 0, 0, 0);
                    acc[m][ctl][rt] = __builtin_amdgcn_mfma_f32_16x16x32_bf16(
                        al[rt], bh, acc[m][ctl][rt], 0, 0, 0);
                }
            }
        }
    }

#pragma unroll
    for (int ctl = 0; ctl < 2; ++ctl) {
        int col = (ct0 + ctl) * 16 + l15;
        float bq_ = bq[col], bk_ = bk[col], bv_ = bv[col];
#pragma unroll
        for (int rt = 0; rt < 4; ++rt) {
#pragma unroll
            for (int reg = 0; reg < 4; ++reg) {
                int row = row0 + rt * 16 + quad * 4 + reg;
                if (row < N_NODES) {
                    q[(size_t)row * 128 + col] = acc[0][ctl][rt][reg] + bq_;
                    unsigned kb = f2bf(acc[1][ctl][rt][reg] + bk_);
                    unsigned vb = f2bf(acc[2][ctl][rt][reg] + bv_);
                    kvp[(size_t)row * 128 + col] = kb | (vb << 16);
                }
            }
        }
    }
}

// degree histogram
__global__ void k_count(const int* __restrict__ src, int* __restrict__ cnt) {
    int e = blockIdx.x * 256 + threadIdx.x;
    if (e < N_EDGES) atomicAdd(&cnt[src[e]], 1);
}

// hierarchical scan over 50000 counts
__global__ __launch_bounds__(1024) void k_scan1(const int* __restrict__ cnt,
                                                int* __restrict__ loc,
                                                int* __restrict__ bsum, int n) {
    __shared__ int buf[1024];
    int t = threadIdx.x;
    int i = blockIdx.x * 1024 + t;
    int val = (i < n) ? cnt[i] : 0;
    buf[t] = val;
    __syncthreads();
    for (int off = 1; off < 1024; off <<= 1) {
        int a = (t >= off) ? buf[t - off] : 0;
        __syncthreads();
        buf[t] += a;
        __syncthreads();
    }
    if (i < n) loc[i] = buf[t];
    if (t == 1023) bsum[blockIdx.x] = buf[1023];
}

__global__ void k_scan2(int* __restrict__ bsum, int nb) {
    int t = threadIdx.x;
    int v = (t < nb) ? bsum[t] : 0;
    for (int off = 1; off < 64; off <<= 1) {
        int a = __shfl_up(v, off);
        if (t >= off) v += a;
    }
    if (t < nb) bsum[t] = v;
}

__global__ void k_scan3(const int* __restrict__ cnt, const int* __restrict__ loc,
                        const int* __restrict__ bsum,
                        int* __restrict__ rowptr, int* __restrict__ cursor, int n) {
    int i = blockIdx.x * 256 + threadIdx.x;
    if (i < n) {
        int off = (i >= 1024) ? bsum[(i >> 10) - 1] : 0;
        int incl = loc[i] + off;
        rowptr[i + 1] = incl;
        cursor[i] = incl - cnt[i];
    }
    if (i == 0) rowptr[0] = 0;
}

// scatter into CSR order: esd[pos] = (dst, dist^2) as one 8B store
__global__ void k_scatter(const int* __restrict__ src, const int* __restrict__ dst,
                          const float* __restrict__ dist, int* __restrict__ cursor,
                          int2* __restrict__ esd) {
    int e = blockIdx.x * 256 + threadIdx.x;
    if (e < N_EDGES) {
        int pos = atomicAdd(&cursor[src[e]], 1);
        float dd = dist[e];
        esd[pos] = make_int2(dst[e], __float_as_int(dd * dd));
    }
}

// FUSED edge+node: one wave per node, 8-edge batched inner loop for MLP.
// Per edge: ONE gather of the packed bf16 kv row (uint2/lane = cols 2l,2l+1).
__global__ __launch_bounds__(256) void k_edge_node(
    const float* __restrict__ q, const unsigned* __restrict__ kvp,
    const float* __restrict__ x,
    const int2* __restrict__ esd, const int* __restrict__ rowptr,
    const float* __restrict__ Wd, const float* __restrict__ bd,
    unsigned short* __restrict__ hupd_hi, unsigned short* __restrict__ hupd_lo,
    float* __restrict__ disp) {
    const int wave = threadIdx.x >> 6, lane = threadIdx.x & 63;
    const int node = blockIdx.x * 4 + wave;           // grid exact: N/4 blocks
    const int h = lane >> 3, sub = lane & 7;          // head, within-head slot
    const int beg = rowptr[node], end = rowptr[node + 1];

    const float2 qv = *(const float2*)(q + (size_t)node * 128 + 2 * lane);
    const float wdh = Wd[h], bdh = bd[h];
    const bool dal = (sub < 3);
    float xs = dal ? x[node * 3 + sub] : 0.f;
    const unsigned colo = 2 * lane;

    float acc0 = 0.f, acc1 = 0.f, s_own = 0.f, da = 0.f;

    for (int cb = beg; cb < end; cb += 64) {
        int idx = cb + lane;
        int dvec = 0; float d2vec = 0.f;
        if (idx < end) {
            int2 ed = esd[idx];
            dvec = ed.x;
            d2vec = __int_as_float(ed.y);
        }
        int clen = min(64, end - cb);
        int i = 0;
        for (; i + 8 <= clen; i += 8) {
            int di[8]; float dd2[8]; uint2 kv2[8]; float xg[8];
#pragma unroll
            for (int j = 0; j < 8; ++j) {
                di[j]  = __shfl(dvec, i + j);
                dd2[j] = __shfl(d2vec, i + j);
            }
#pragma unroll
            for (int j = 0; j < 8; ++j)
                kv2[j] = *(const uint2*)(kvp + (unsigned)di[j] * 128u + colo);
#pragma unroll
            for (int j = 0; j < 8; ++j)
                xg[j] = dal ? x[(unsigned)di[j] * 3u + sub] : 0.f;
#pragma unroll
            for (int j = 0; j < 8; ++j) {
                float k0 = __builtin_bit_cast(float, kv2[j].x << 16);
                float v0 = __builtin_bit_cast(float, kv2[j].x & 0xFFFF0000u);
                float k1 = __builtin_bit_cast(float, kv2[j].y << 16);
                float v1 = __builtin_bit_cast(float, kv2[j].y & 0xFFFF0000u);
                float p = qv.x * k0 + qv.y * k1;
                p += __shfl_xor(p, 1);
                p += __shfl_xor(p, 2);
                p += __shfl_xor(p, 4);                 // all 8 lanes of head h: full dot
                float w = __expf(p * 0.25f - (dd2[j] * wdh + bdh));
                s_own += w;
                acc0 += v0 * w;
                acc1 += v1 * w;
                da += (xg[j] - xs) * w;                // xs=xg=0 on non-da lanes
            }
        }
        for (; i < clen; ++i) {
            int dij  = __shfl(dvec, i);
            float d2 = __shfl(d2vec, i);
            uint2 kv2 = *(const uint2*)(kvp + (unsigned)dij * 128u + colo);
            float xgj = dal ? x[(unsigned)dij * 3u + sub] : 0.f;
            float k0 = __builtin_bit_cast(float, kv2.x << 16);
            float v0 = __builtin_bit_cast(float, kv2.x & 0xFFFF0000u);
            float k1 = __builtin_bit_cast(float, kv2.y << 16);
            float v1 = __builtin_bit_cast(float, kv2.y & 0xFFFF0000u);
            float p = qv.x * k0 + qv.y * k1;
            p += __shfl_xor(p, 1);
            p += __shfl_xor(p, 2);
            p += __shfl_xor(p, 4);
            float w = __expf(p * 0.25f - (d2 * wdh + bdh));
            s_own += w;
            acc0 += v0 * w;
            acc1 += v1 * w;
            da += (xgj - xs) * w;
        }
    }

    float inva = 1.f / fmaxf(s_own, 1e-9f);
    float o0 = acc0 * inva, o1 = acc1 * inva;
    unsigned short h0 = f2bf(o0), h1 = f2bf(o1);
    unsigned short l0 = f2bf(o0 - bf2f(h0)), l1 = f2bf(o1 - bf2f(h1));
    ((unsigned*)hupd_hi)[(size_t)node * 64 + lane] = (unsigned)h0 | ((unsigned)h1 << 16);
    ((unsigned*)hupd_lo)[(size_t)node * 64 + lane] = (unsigned)l0 | ((unsigned)l1 << 16);

    da *= 0.125f * inva;
    da += __shfl_xor(da, 8);
    da += __shfl_xor(da, 16);
    da += __shfl_xor(da, 32);
    if (lane < 3) disp[node * 3 + lane] = da;
}

// fused MFMA epilogue: hout = h + hupd@Wo + bo (GEMM1); hout staged in
// per-wave padded LDS; GEMM2 = hout@Wg1; gate = tanh(sum silu(.)*Wg2);
// xout = x + gate*disp.  Block=128 (2 waves), 32 rows/wave (rt=2).
__global__ __launch_bounds__(128) void k_hout_gate(
    const float* __restrict__ h,
    const unsigned short* __restrict__ hupd_hi, const unsigned short* __restrict__ hupd_lo,
    const unsigned short* __restrict__ wsp,
    const float* __restrict__ bo, const float* __restrict__ bg1,
    const float* __restrict__ Wg2, const float* __restrict__ bg2,
    const float* __restrict__ x, const float* __restrict__ disp,
    float* __restrict__ hout, float* __restrict__ xout) {
    __shared__ float hb[2][32 * 132];                 // +4 dword pad per row
    const int wave = threadIdx.x >> 6, lane = threadIdx.x & 63;
    const int quad = lane >> 4, l15 = lane & 15;
    const int rowW = blockIdx.x * 64 + wave * 32;     // wave's 32 rows
    float* hbw = hb[wave];

    // ---- GEMM1: hupd @ Wo (m=3) ----
    floatx4 acc[8][2];
#pragma unroll
    for (int c = 0; c < 8; ++c)
#pragma unroll
        for (int r = 0; r < 2; ++r) acc[c][r] = (floatx4){0.f, 0.f, 0.f, 0.f};
#pragma unroll
    for (int kc = 0; kc < 4; ++kc) {
        short8 ah[2], al[2];
#pragma unroll
        for (int rt = 0; rt < 2; ++rt) {
            int row = rowW + rt * 16 + l15;
            if (row >= N_NODES) row = N_NODES - 1;
            size_t aoff = (size_t)row * 128 + kc * 32 + quad * 8;
            ah[rt] = *(const short8*)(hupd_hi + aoff);
            al[rt] = *(const short8*)(hupd_lo + aoff);
        }
#pragma unroll
        for (int ct = 0; ct < 8; ++ct) {
            unsigned fb = ((((unsigned)(3 * 4 + kc) * 8 + ct) * 2) * 64 + lane) * 8;
            short8 bh = *(const short8*)(wsp + fb);
            short8 bl = *(const short8*)(wsp + fb + 512);
#pragma unroll
            for (int rt = 0; rt < 2; ++rt) {
                acc[ct][rt] = __builtin_amdgcn_mfma_f32_16x16x32_bf16(ah[rt], bh, acc[ct][rt], 0, 0, 0);
                acc[ct][rt] = __builtin_amdgcn_mfma_f32_16x16x32_bf16(ah[rt], bl, acc[ct][rt], 0, 0, 0);
                acc[ct][rt] = __builtin_amdgcn_mfma_f32_16x16x32_bf16(al[rt], bh, acc[ct][rt], 0, 0, 0);
            }
        }
    }

    // epilogue 1: add h + bo, write hout (global) + LDS tile
#pragma unroll
    for (int ct = 0; ct < 8; ++ct) {
        int col = ct * 16 + l15;
        float bias = bo[col];
#pragma unroll
        for (int rt = 0; rt < 2; ++rt) {
#pragma unroll
            for (int reg = 0; reg < 4; ++reg) {
                int row = rowW + rt * 16 + quad * 4 + reg;
                float val = acc[ct][rt][reg] + bias;
                if (row < N_NODES) {
                    val += h[(size_t)row * 128 + col];
                    hout[(size_t)row * 128 + col] = val;
                }
                hbw[(rt * 16 + quad * 4 + reg) * 132 + col] = val;
            }
        }
    }
    __asm__ volatile("s_waitcnt lgkmcnt(0)" ::: "memory");

    // ---- GEMM2: hout @ Wg1 (m=4), A-frags read from LDS ----
    floatx4 acc2[8][2];
#pragma unroll
    for (int c = 0; c < 8; ++c)
#pragma unroll
        for (int r = 0; r < 2; ++r) acc2[c][r] = (floatx4){0.f, 0.f, 0.f, 0.f};
#pragma unroll
    for (int kc = 0; kc < 4; ++kc) {
        short8 ah2[2], al2[2];
#pragma unroll
        for (int rt = 0; rt < 2; ++rt) {
            const float* ap = hbw + (rt * 16 + l15) * 132 + kc * 32 + quad * 8;
            float4 f0 = *(const float4*)(ap);
            float4 f1 = *(const float4*)(ap + 4);
            float fv[8] = {f0.x, f0.y, f0.z, f0.w, f1.x, f1.y, f1.z, f1.w};
#pragma unroll
            for (int j = 0; j < 8; ++j) {
                unsigned short hi = f2bf(fv[j]);
                ah2[rt][j] = (short)hi;
                al2[rt][j] = (short)f2bf(fv[j] - bf2f(hi));
            }
        }
#pragma unroll
        for (int ct = 0; ct < 8; ++ct) {
            unsigned fb = ((((unsigned)(4 * 4 + kc) * 8 + ct) * 2) * 64 + lane) * 8;
            short8 bh = *(const short8*)(wsp + fb);
            short8 bl = *(const short8*)(wsp + fb + 512);
#pragma unroll
            for (int rt = 0; rt < 2; ++rt) {
                acc2[ct][rt] = __builtin_amdgcn_mfma_f32_16x16x32_bf16(ah2[rt], bh, acc2[ct][rt], 0, 0, 0);
                acc2[ct][rt] = __builtin_amdgcn_mfma_f32_16x16x32_bf16(ah2[rt], bl, acc2[ct][rt], 0, 0, 0);
                acc2[ct][rt] = __builtin_amdgcn_mfma_f32_16x16x32_bf16(al2[rt], bh, acc2[ct][rt], 0, 0, 0);
            }
        }
    }

    // epilogue 2: silu * Wg2, reduce cols -> gate -> xout
    float pr[2][4] = {{0.f, 0.f, 0.f, 0.f}, {0.f, 0.f, 0.f, 0.f}};
#pragma unroll
    for (int ct = 0; ct < 8; ++ct) {
        int col = ct * 16 + l15;
        float b1 = bg1[col];
        float w2 = Wg2[col];
#pragma unroll
        for (int rt = 0; rt < 2; ++rt) {
#pragma unroll
            for (int reg = 0; reg < 4; ++reg) {
                float z = acc2[ct][rt][reg] + b1;
                pr[rt][reg] += (z / (1.f + __expf(-z))) * w2;
            }
        }
    }
#pragma unroll
    for (int off = 1; off < 16; off <<= 1) {
#pragma unroll
        for (int rt = 0; rt < 2; ++rt)
#pragma unroll
            for (int reg = 0; reg < 4; ++reg) pr[rt][reg] += __shfl_xor(pr[rt][reg], off);
    }
    if (l15 == 0) {
        float b2 = bg2[0];
#pragma unroll
        for (int rt = 0; rt < 2; ++rt) {
#pragma unroll
            for (int reg = 0; reg < 4; ++reg) {
                int row = rowW + rt * 16 + quad * 4 + reg;
                if (row < N_NODES) {
                    float g = tanhf(pr[rt][reg] + b2);
#pragma unroll
                    for (int dd = 0; dd < 3; ++dd) {
                        int oo = row * 3 + dd;
                        xout[oo] = x[oo] + g * disp[oo];
                    }
                }
            }
        }
    }
}

extern "C" void kernel_launch(void* const* d_in, const int* in_sizes, int n_in,
                              void* d_out, int out_size, void* d_ws, size_t ws_size,
                              hipStream_t stream) {
    const float* h    = (const float*)d_in[0];
    const float* x    = (const float*)d_in[1];
    const int*   src  = (const int*)d_in[2];
    const int*   dst  = (const int*)d_in[3];
    const float* dist = (const float*)d_in[4];
    const float* Wq = (const float*)d_in[5];  const float* bq = (const float*)d_in[6];
    const float* Wk = (const float*)d_in[7];  const float* bk = (const float*)d_in[8];
    const float* Wv = (const float*)d_in[9];  const float* bv = (const float*)d_in[10];
    const float* Wo = (const float*)d_in[11]; const float* bo = (const float*)d_in[12];
    const float* Wd = (const float*)d_in[13]; const float* bd = (const float*)d_in[14];
    const float* Wg1 = (const float*)d_in[15]; const float* bg1 = (const float*)d_in[16];
    const float* Wg2 = (const float*)d_in[17]; const float* bg2 = (const float*)d_in[18];

    float* ws    = (float*)d_ws;
    float* q     = ws + OFF_Q;
    unsigned* kvp = (unsigned*)(ws + OFF_KV);
    float* disp  = ws + OFF_DISP;
    int* cnt     = (int*)(ws + OFF_CNT);
    int* rowptr  = (int*)(ws + OFF_ROWPTR);
    int* cursor  = (int*)(ws + OFF_CURSOR);
    int2* esd    = (int2*)(ws + OFF_ESD);
    unsigned short* wsp = (unsigned short*)(ws + OFF_WSPLIT);
    // scan scratch in q region, consumed before k_qkv_mfma writes q
    int* loc    = (int*)(ws + OFF_Q);
    int* bsum   = (int*)(ws + OFF_Q + 500000u);
    unsigned short* hupd_hi = (unsigned short*)(ws + OFF_HHI);
    unsigned short* hupd_lo = (unsigned short*)(ws + OFF_HLO);
    float* hout = (float*)d_out;
    float* xout = hout + (size_t)N_NODES * HIDDEN;

    const int nscan = (N_NODES + 1023) / 1024;    // 49

    k_split_w<<<320, 256, 0, stream>>>(Wq, Wk, Wv, Wo, Wg1, wsp);
    k_zero_int<<<(N_NODES + 255) / 256, 256, 0, stream>>>(cnt, N_NODES);
    k_count<<<(N_EDGES + 255) / 256, 256, 0, stream>>>(src, cnt);
    k_scan1<<<nscan, 1024, 0, stream>>>(cnt, loc, bsum, N_NODES);
    k_scan2<<<1, 64, 0, stream>>>(bsum, nscan);
    k_scan3<<<(N_NODES + 255) / 256, 256, 0, stream>>>(cnt, loc, bsum, rowptr, cursor, N_NODES);
    k_scatter<<<(N_EDGES + 255) / 256, 256, 0, stream>>>(src, dst, dist, cursor, esd);
    k_qkv_mfma<<<(N_NODES + 63) / 64, 256, 0, stream>>>(h, wsp, bq, bk, bv, q, kvp);
    k_edge_node<<<N_NODES / 4, 256, 0, stream>>>(q, kvp, x, esd, rowptr,
                                                 Wd, bd, hupd_hi, hupd_lo, disp);
    k_hout_gate<<<(N_NODES + 63) / 64, 128, 0, stream>>>(h, hupd_hi, hupd_lo, wsp,
                                                         bo, bg1, Wg2, bg2,
                                                         x, disp, hout, xout);
}

// Round 10
// 286.883 us; speedup vs baseline: 1.0538x; 1.0538x over previous
//
#include <hip/hip_runtime.h>
#include <math.h>

#define N_NODES 50000
#define N_EDGES 500000
#define HIDDEN 128
#define HEADS 8
#define HEAD_DIM 16

typedef __attribute__((ext_vector_type(8))) short short8;     // 8 bf16 (4 VGPRs) MFMA A/B frag
typedef __attribute__((ext_vector_type(4))) float floatx4;    // MFMA C/D frag

// workspace layout, element offsets (4-byte units)
#define OFF_Q       0u           // scan scratch (pre-qkv) -> q fp32 [50000x128]
#define OFF_KV      6400000u     // kv packed bf16 pairs [50000x128] (k lo16, v hi16)
#define OFF_HHI     12800000u    // hupd_hi bf16 [50000x128]
#define OFF_HLO     16000000u    // hupd_lo bf16 [50000x128]
#define OFF_DISP    19200000u    // 150,000 floats
#define OFF_CNT     19350016u    // 50,000 ints
#define OFF_ROWPTR  19400032u    // 50,001 ints
#define OFF_CURSOR  19450048u    // 50,000 ints
#define OFF_ESD     19500064u    // 1,000,000 ints (int2 per edge: dst, dist^2 bits, CSR order)
#define OFF_WSPLIT  20500064u    // W{q,k,v,o,g1} split-bf16 frag order: 81,920 float slots
// end: 20,581,984 floats = 82.3 MB

static __device__ __forceinline__ unsigned short f2bf(float f) {
    unsigned u = __builtin_bit_cast(unsigned, f);
    unsigned r = (u + 0x7FFFu + ((u >> 16) & 1u)) >> 16;      // RNE
    return (unsigned short)r;
}
static __device__ __forceinline__ float bf2f(unsigned short s) {
    return __builtin_bit_cast(float, (unsigned)s << 16);
}

__global__ void k_zero_int(int* __restrict__ p, int n) {
    int i = blockIdx.x * 256 + threadIdx.x;
    if (i < n) p[i] = 0;
}

// repack W{q,k,v,o,g1} into split-bf16 MFMA B-fragment order:
// frag(m,kc,ct,hilo): 64 lanes x 8 bf16, lane holds B[k=kc*32+(lane>>4)*8+j][n=ct*16+(lane&15)]
__global__ void k_split_w(const float* __restrict__ Wq, const float* __restrict__ Wk,
                          const float* __restrict__ Wv, const float* __restrict__ Wo,
                          const float* __restrict__ Wg1, unsigned short* __restrict__ ws) {
    int t = blockIdx.x * 256 + threadIdx.x;          // grid exact: 5*16384
    int m = t >> 14, r = t & 16383;
    int k = r >> 7, n = r & 127;
    const float* W = (m == 0) ? Wq : (m == 1) ? Wk : (m == 2) ? Wv : (m == 3) ? Wo : Wg1;
    float x = W[k * 128 + n];
    int kc = k >> 5, kin = k & 31, quad = kin >> 3, j = kin & 7;
    int ct = n >> 4, nin = n & 15, lane = quad * 16 + nin;
    unsigned base = ((((unsigned)(m * 4 + kc) * 8 + ct) * 2) * 64 + lane) * 8 + j;
    unsigned short a = f2bf(x);
    ws[base] = a;                                    // hilo=0
    ws[base + 512] = f2bf(x - bf2f(a));              // hilo=1 (+64 lanes*8)
}

// q/k/v via split-bf16 MFMA, h split hi/lo in-register (no split_h kernel).
// 32 rows/block (rt=2), 4 waves; wave w owns col-tiles {2w,2w+1} for all 3 mats.
// q written fp32; k,v packed as bf16 pairs (k lo16, v hi16).
__global__ __launch_bounds__(256) void k_qkv_mfma(
    const float* __restrict__ h, const unsigned short* __restrict__ wsp,
    const float* __restrict__ bq, const float* __restrict__ bk, const float* __restrict__ bv,
    float* __restrict__ q, unsigned* __restrict__ kvp) {
    const int wave = threadIdx.x >> 6, lane = threadIdx.x & 63;
    const int quad = lane >> 4, l15 = lane & 15;
    const int ct0 = wave * 2;
    const int row0 = blockIdx.x * 32;

    floatx4 acc[3][2][2];                            // [mat][ctl][rt]
#pragma unroll
    for (int m = 0; m < 3; ++m)
#pragma unroll
        for (int c = 0; c < 2; ++c)
#pragma unroll
            for (int r = 0; r < 2; ++r) acc[m][c][r] = (floatx4){0.f, 0.f, 0.f, 0.f};

#pragma unroll
    for (int kc = 0; kc < 4; ++kc) {
        short8 ah[2], al[2];
#pragma unroll
        for (int rt = 0; rt < 2; ++rt) {
            int row = row0 + rt * 16 + l15;
            if (row >= N_NODES) row = N_NODES - 1;
            const float* hp = h + (size_t)row * 128 + kc * 32 + quad * 8;
            float4 f0 = *(const float4*)(hp);
            float4 f1 = *(const float4*)(hp + 4);
            float fv[8] = {f0.x, f0.y, f0.z, f0.w, f1.x, f1.y, f1.z, f1.w};
#pragma unroll
            for (int j = 0; j < 8; ++j) {
                unsigned short hi = f2bf(fv[j]);
                ah[rt][j] = (short)hi;
                al[rt][j] = (short)f2bf(fv[j] - bf2f(hi));
            }
        }
#pragma unroll
        for (int m = 0; m < 3; ++m) {
#pragma unroll
            for (int ctl = 0; ctl < 2; ++ctl) {
                unsigned fb = ((((unsigned)(m * 4 + kc) * 8 + (ct0 + ctl)) * 2) * 64 + lane) * 8;
                short8 bh = *(const short8*)(wsp + fb);
                short8 bl = *(const short8*)(wsp + fb + 512);
#pragma unroll
                for (int rt = 0; rt < 2; ++rt) {
                    acc[m][ctl][rt] = __builtin_amdgcn_mfma_f32_16x16x32_bf16(
                        ah[rt], bh, acc[m][ctl][rt], 0, 0, 0);
                    acc[m][ctl][rt] = __builtin_amdgcn_mfma_f32_16x16x32_bf16(
                        ah[rt], bl, acc[m][ctl][rt], 0, 0, 0);
                    acc[m][ctl][rt] = __builtin_amdgcn_mfma_f32_16x16x32_bf16(
                        al[rt], bh, acc[m][ctl][rt], 0, 0, 0);
                }
            }
        }
    }

#pragma unroll
    for (int ctl = 0; ctl < 2; ++ctl) {
        int col = (ct0 + ctl) * 16 + l15;
        float bq_ = bq[col], bk_ = bk[col], bv_ = bv[col];
#pragma unroll
        for (int rt = 0; rt < 2; ++rt) {
#pragma unroll
            for (int reg = 0; reg < 4; ++reg) {
                int row = row0 + rt * 16 + quad * 4 + reg;
                if (row < N_NODES) {
                    q[(size_t)row * 128 + col] = acc[0][ctl][rt][reg] + bq_;
                    unsigned kb = f2bf(acc[1][ctl][rt][reg] + bk_);
                    unsigned vb = f2bf(acc[2][ctl][rt][reg] + bv_);
                    kvp[(size_t)row * 128 + col] = kb | (vb << 16);
                }
            }
        }
    }
}

// degree histogram
__global__ void k_count(const int* __restrict__ src, int* __restrict__ cnt) {
    int e = blockIdx.x * 256 + threadIdx.x;
    if (e < N_EDGES) atomicAdd(&cnt[src[e]], 1);
}

// hierarchical scan over 50000 counts
__global__ __launch_bounds__(1024) void k_scan1(const int* __restrict__ cnt,
                                                int* __restrict__ loc,
                                                int* __restrict__ bsum, int n) {
    __shared__ int buf[1024];
    int t = threadIdx.x;
    int i = blockIdx.x * 1024 + t;
    int val = (i < n) ? cnt[i] : 0;
    buf[t] = val;
    __syncthreads();
    for (int off = 1; off < 1024; off <<= 1) {
        int a = (t >= off) ? buf[t - off] : 0;
        __syncthreads();
        buf[t] += a;
        __syncthreads();
    }
    if (i < n) loc[i] = buf[t];
    if (t == 1023) bsum[blockIdx.x] = buf[1023];
}

__global__ void k_scan2(int* __restrict__ bsum, int nb) {
    int t = threadIdx.x;
    int v = (t < nb) ? bsum[t] : 0;
    for (int off = 1; off < 64; off <<= 1) {
        int a = __shfl_up(v, off);
        if (t >= off) v += a;
    }
    if (t < nb) bsum[t] = v;
}

__global__ void k_scan3(const int* __restrict__ cnt, const int* __restrict__ loc,
                        const int* __restrict__ bsum,
                        int* __restrict__ rowptr, int* __restrict__ cursor, int n) {
    int i = blockIdx.x * 256 + threadIdx.x;
    if (i < n) {
        int off = (i >= 1024) ? bsum[(i >> 10) - 1] : 0;
        int incl = loc[i] + off;
        rowptr[i + 1] = incl;
        cursor[i] = incl - cnt[i];
    }
    if (i == 0) rowptr[0] = 0;
}

// scatter into CSR order: esd[pos] = (dst, dist^2) as one 8B store
__global__ void k_scatter(const int* __restrict__ src, const int* __restrict__ dst,
                          const float* __restrict__ dist, int* __restrict__ cursor,
                          int2* __restrict__ esd) {
    int e = blockIdx.x * 256 + threadIdx.x;
    if (e < N_EDGES) {
        int pos = atomicAdd(&cursor[src[e]], 1);
        float dd = dist[e];
        esd[pos] = make_int2(dst[e], __float_as_int(dd * dd));
    }
}

// FUSED edge+node: one wave per node, 4-edge batched inner loop (round-8
// proven config: VGPR 32, ~63% occupancy, ~3.3 TB/s).
// Per edge: ONE gather of the packed bf16 kv row (uint2/lane = cols 2l,2l+1).
__global__ __launch_bounds__(256) void k_edge_node(
    const float* __restrict__ q, const unsigned* __restrict__ kvp,
    const float* __restrict__ x,
    const int2* __restrict__ esd, const int* __restrict__ rowptr,
    const float* __restrict__ Wd, const float* __restrict__ bd,
    unsigned short* __restrict__ hupd_hi, unsigned short* __restrict__ hupd_lo,
    float* __restrict__ disp) {
    const int wave = threadIdx.x >> 6, lane = threadIdx.x & 63;
    const int node = blockIdx.x * 4 + wave;           // grid exact: N/4 blocks
    const int h = lane >> 3, sub = lane & 7;          // head, within-head slot
    const int beg = rowptr[node], end = rowptr[node + 1];

    const float2 qv = *(const float2*)(q + (size_t)node * 128 + 2 * lane);
    const float wdh = Wd[h], bdh = bd[h];
    const bool dal = (sub < 3);
    float xs = dal ? x[node * 3 + sub] : 0.f;
    const unsigned colo = 2 * lane;

    float acc0 = 0.f, acc1 = 0.f, s_own = 0.f, da = 0.f;

    for (int cb = beg; cb < end; cb += 64) {
        int idx = cb + lane;
        int dvec = 0; float d2vec = 0.f;
        if (idx < end) {
            int2 ed = esd[idx];
            dvec = ed.x;
            d2vec = __int_as_float(ed.y);
        }
        int clen = min(64, end - cb);
        int i = 0;
        for (; i + 4 <= clen; i += 4) {
            int di[4]; float dd2[4]; uint2 kv2[4]; float xg[4];
#pragma unroll
            for (int j = 0; j < 4; ++j) {
                di[j]  = __shfl(dvec, i + j);
                dd2[j] = __shfl(d2vec, i + j);
            }
#pragma unroll
            for (int j = 0; j < 4; ++j)
                kv2[j] = *(const uint2*)(kvp + (unsigned)di[j] * 128u + colo);
#pragma unroll
            for (int j = 0; j < 4; ++j)
                xg[j] = dal ? x[(unsigned)di[j] * 3u + sub] : 0.f;
#pragma unroll
            for (int j = 0; j < 4; ++j) {
                float k0 = __builtin_bit_cast(float, kv2[j].x << 16);
                float v0 = __builtin_bit_cast(float, kv2[j].x & 0xFFFF0000u);
                float k1 = __builtin_bit_cast(float, kv2[j].y << 16);
                float v1 = __builtin_bit_cast(float, kv2[j].y & 0xFFFF0000u);
                float p = qv.x * k0 + qv.y * k1;
                p += __shfl_xor(p, 1);
                p += __shfl_xor(p, 2);
                p += __shfl_xor(p, 4);                 // all 8 lanes of head h: full dot
                float w = __expf(p * 0.25f - (dd2[j] * wdh + bdh));
                s_own += w;
                acc0 += v0 * w;
                acc1 += v1 * w;
                da += (xg[j] - xs) * w;                // xs=xg=0 on non-da lanes
            }
        }
        for (; i < clen; ++i) {
            int dij  = __shfl(dvec, i);
            float d2 = __shfl(d2vec, i);
            uint2 kv2 = *(const uint2*)(kvp + (unsigned)dij * 128u + colo);
            float xgj = dal ? x[(unsigned)dij * 3u + sub] : 0.f;
            float k0 = __builtin_bit_cast(float, kv2.x << 16);
            float v0 = __builtin_bit_cast(float, kv2.x & 0xFFFF0000u);
            float k1 = __builtin_bit_cast(float, kv2.y << 16);
            float v1 = __builtin_bit_cast(float, kv2.y & 0xFFFF0000u);
            float p = qv.x * k0 + qv.y * k1;
            p += __shfl_xor(p, 1);
            p += __shfl_xor(p, 2);
            p += __shfl_xor(p, 4);
            float w = __expf(p * 0.25f - (d2 * wdh + bdh));
            s_own += w;
            acc0 += v0 * w;
            acc1 += v1 * w;
            da += (xgj - xs) * w;
        }
    }

    float inva = 1.f / fmaxf(s_own, 1e-9f);
    float o0 = acc0 * inva, o1 = acc1 * inva;
    unsigned short h0 = f2bf(o0), h1 = f2bf(o1);
    unsigned short l0 = f2bf(o0 - bf2f(h0)), l1 = f2bf(o1 - bf2f(h1));
    ((unsigned*)hupd_hi)[(size_t)node * 64 + lane] = (unsigned)h0 | ((unsigned)h1 << 16);
    ((unsigned*)hupd_lo)[(size_t)node * 64 + lane] = (unsigned)l0 | ((unsigned)l1 << 16);

    da *= 0.125f * inva;
    da += __shfl_xor(da, 8);
    da += __shfl_xor(da, 16);
    da += __shfl_xor(da, 32);
    if (lane < 3) disp[node * 3 + lane] = da;
}

// fused MFMA epilogue (round-8 proven geometry: block=256, 16 rows/wave):
// hout = h + hupd@Wo + bo (GEMM1); hout staged in per-wave padded LDS;
// GEMM2 = hout@Wg1; gate = tanh(sum silu(.)*Wg2); xout = x + gate*disp.
__global__ __launch_bounds__(256) void k_hout_gate(
    const float* __restrict__ h,
    const unsigned short* __restrict__ hupd_hi, const unsigned short* __restrict__ hupd_lo,
    const unsigned short* __restrict__ wsp,
    const float* __restrict__ bo, const float* __restrict__ bg1,
    const float* __restrict__ Wg2, const float* __restrict__ bg2,
    const float* __restrict__ x, const float* __restrict__ disp,
    float* __restrict__ hout, float* __restrict__ xout) {
    __shared__ float hb[4][16 * 132];                 // +4 dword pad per row
    const int wave = threadIdx.x >> 6, lane = threadIdx.x & 63;
    const int quad = lane >> 4, l15 = lane & 15;
    const int row0 = blockIdx.x * 64 + wave * 16;
    float* hbw = hb[wave];

    // ---- GEMM1: hupd @ Wo (m=3) ----
    floatx4 acc[8];
#pragma unroll
    for (int c = 0; c < 8; ++c) acc[c] = (floatx4){0.f, 0.f, 0.f, 0.f};
#pragma unroll
    for (int kc = 0; kc < 4; ++kc) {
        int row = row0 + l15;
        if (row >= N_NODES) row = N_NODES - 1;
        size_t aoff = (size_t)row * 128 + kc * 32 + quad * 8;
        short8 ah = *(const short8*)(hupd_hi + aoff);
        short8 al = *(const short8*)(hupd_lo + aoff);
#pragma unroll
        for (int ct = 0; ct < 8; ++ct) {
            unsigned fb = ((((unsigned)(3 * 4 + kc) * 8 + ct) * 2) * 64 + lane) * 8;
            short8 bh = *(const short8*)(wsp + fb);
            short8 bl = *(const short8*)(wsp + fb + 512);
            acc[ct] = __builtin_amdgcn_mfma_f32_16x16x32_bf16(ah, bh, acc[ct], 0, 0, 0);
            acc[ct] = __builtin_amdgcn_mfma_f32_16x16x32_bf16(ah, bl, acc[ct], 0, 0, 0);
            acc[ct] = __builtin_amdgcn_mfma_f32_16x16x32_bf16(al, bh, acc[ct], 0, 0, 0);
        }
    }

    // epilogue 1: add h + bo, write hout (global) + LDS tile
#pragma unroll
    for (int ct = 0; ct < 8; ++ct) {
        int col = ct * 16 + l15;
        float bias = bo[col];
#pragma unroll
        for (int reg = 0; reg < 4; ++reg) {
            int row = row0 + quad * 4 + reg;
            float val = acc[ct][reg] + bias;
            if (row < N_NODES) {
                val += h[(size_t)row * 128 + col];
                hout[(size_t)row * 128 + col] = val;
            }
            hbw[(quad * 4 + reg) * 132 + col] = val;
        }
    }
    __asm__ volatile("s_waitcnt lgkmcnt(0)" ::: "memory");

    // ---- GEMM2: hout @ Wg1 (m=4), A-frags read from LDS ----
    floatx4 acc2[8];
#pragma unroll
    for (int c = 0; c < 8; ++c) acc2[c] = (floatx4){0.f, 0.f, 0.f, 0.f};
#pragma unroll
    for (int kc = 0; kc < 4; ++kc) {
        const float* ap = hbw + l15 * 132 + kc * 32 + quad * 8;
        float4 f0 = *(const float4*)(ap);
        float4 f1 = *(const float4*)(ap + 4);
        float fv[8] = {f0.x, f0.y, f0.z, f0.w, f1.x, f1.y, f1.z, f1.w};
        short8 ah, al;
#pragma unroll
        for (int j = 0; j < 8; ++j) {
            unsigned short hi = f2bf(fv[j]);
            ah[j] = (short)hi;
            al[j] = (short)f2bf(fv[j] - bf2f(hi));
        }
#pragma unroll
        for (int ct = 0; ct < 8; ++ct) {
            unsigned fb = ((((unsigned)(4 * 4 + kc) * 8 + ct) * 2) * 64 + lane) * 8;
            short8 bh = *(const short8*)(wsp + fb);
            short8 bl = *(const short8*)(wsp + fb + 512);
            acc2[ct] = __builtin_amdgcn_mfma_f32_16x16x32_bf16(ah, bh, acc2[ct], 0, 0, 0);
            acc2[ct] = __builtin_amdgcn_mfma_f32_16x16x32_bf16(ah, bl, acc2[ct], 0, 0, 0);
            acc2[ct] = __builtin_amdgcn_mfma_f32_16x16x32_bf16(al, bh, acc2[ct], 0, 0, 0);
        }
    }

    // epilogue 2: silu * Wg2, reduce cols -> gate -> xout
    float pr[4] = {0.f, 0.f, 0.f, 0.f};
#pragma unroll
    for (int ct = 0; ct < 8; ++ct) {
        int col = ct * 16 + l15;
        float b1 = bg1[col];
        float w2 = Wg2[col];
#pragma unroll
        for (int reg = 0; reg < 4; ++reg) {
            float z = acc2[ct][reg] + b1;
            pr[reg] += (z / (1.f + __expf(-z))) * w2;
        }
    }
#pragma unroll
    for (int off = 1; off < 16; off <<= 1) {
#pragma unroll
        for (int reg = 0; reg < 4; ++reg) pr[reg] += __shfl_xor(pr[reg], off);
    }
    if (l15 == 0) {
        float b2 = bg2[0];
#pragma unroll
        for (int reg = 0; reg < 4; ++reg) {
            int row = row0 + quad * 4 + reg;
            if (row < N_NODES) {
                float g = tanhf(pr[reg] + b2);
#pragma unroll
                for (int dd = 0; dd < 3; ++dd) {
                    int oo = row * 3 + dd;
                    xout[oo] = x[oo] + g * disp[oo];
                }
            }
        }
    }
}

extern "C" void kernel_launch(void* const* d_in, const int* in_sizes, int n_in,
                              void* d_out, int out_size, void* d_ws, size_t ws_size,
                              hipStream_t stream) {
    const float* h    = (const float*)d_in[0];
    const float* x    = (const float*)d_in[1];
    const int*   src  = (const int*)d_in[2];
    const int*   dst  = (const int*)d_in[3];
    const float* dist = (const float*)d_in[4];
    const float* Wq = (const float*)d_in[5];  const float* bq = (const float*)d_in[6];
    const float* Wk = (const float*)d_in[7];  const float* bk = (const float*)d_in[8];
    const float* Wv = (const float*)d_in[9];  const float* bv = (const float*)d_in[10];
    const float* Wo = (const float*)d_in[11]; const float* bo = (const float*)d_in[12];
    const float* Wd = (const float*)d_in[13]; const float* bd = (const float*)d_in[14];
    const float* Wg1 = (const float*)d_in[15]; const float* bg1 = (const float*)d_in[16];
    const float* Wg2 = (const float*)d_in[17]; const float* bg2 = (const float*)d_in[18];

    float* ws    = (float*)d_ws;
    float* q     = ws + OFF_Q;
    unsigned* kvp = (unsigned*)(ws + OFF_KV);
    float* disp  = ws + OFF_DISP;
    int* cnt     = (int*)(ws + OFF_CNT);
    int* rowptr  = (int*)(ws + OFF_ROWPTR);
    int* cursor  = (int*)(ws + OFF_CURSOR);
    int2* esd    = (int2*)(ws + OFF_ESD);
    unsigned short* wsp = (unsigned short*)(ws + OFF_WSPLIT);
    // scan scratch in q region, consumed before k_qkv_mfma writes q
    int* loc    = (int*)(ws + OFF_Q);
    int* bsum   = (int*)(ws + OFF_Q + 500000u);
    unsigned short* hupd_hi = (unsigned short*)(ws + OFF_HHI);
    unsigned short* hupd_lo = (unsigned short*)(ws + OFF_HLO);
    float* hout = (float*)d_out;
    float* xout = hout + (size_t)N_NODES * HIDDEN;

    const int nscan = (N_NODES + 1023) / 1024;    // 49

    k_split_w<<<320, 256, 0, stream>>>(Wq, Wk, Wv, Wo, Wg1, wsp);
    k_zero_int<<<(N_NODES + 255) / 256, 256, 0, stream>>>(cnt, N_NODES);
    k_count<<<(N_EDGES + 255) / 256, 256, 0, stream>>>(src, cnt);
    k_scan1<<<nscan, 1024, 0, stream>>>(cnt, loc, bsum, N_NODES);
    k_scan2<<<1, 64, 0, stream>>>(bsum, nscan);
    k_scan3<<<(N_NODES + 255) / 256, 256, 0, stream>>>(cnt, loc, bsum, rowptr, cursor, N_NODES);
    k_scatter<<<(N_EDGES + 255) / 256, 256, 0, stream>>>(src, dst, dist, cursor, esd);
    k_qkv_mfma<<<(N_NODES + 31) / 32, 256, 0, stream>>>(h, wsp, bq, bk, bv, q, kvp);
    k_edge_node<<<N_NODES / 4, 256, 0, stream>>>(q, kvp, x, esd, rowptr,
                                                 Wd, bd, hupd_hi, hupd_lo, disp);
    k_hout_gate<<<(N_NODES + 63) / 64, 256, 0, stream>>>(h, hupd_hi, hupd_lo, wsp,
                                                         bo, bg1, Wg2, bg2,
                                                         x, disp, hout, xout);
}

// Round 11
// 262.699 us; speedup vs baseline: 1.1508x; 1.0921x over previous
//
#include <hip/hip_runtime.h>
#include <math.h>

#define N_NODES 50000
#define N_EDGES 500000
#define HIDDEN 128
#define HEADS 8
#define HEAD_DIM 16

#define QKV_BLOCKS 1563          // ceil(50000/32)
#define SCAT_BLOCKS 1954         // ceil(500000/256)
#define SPLITW_BLOCKS 320        // 5*16384/256
#define ZERO_BLOCKS 196          // ceil(50000/256)

typedef __attribute__((ext_vector_type(8))) short short8;     // 8 bf16 (4 VGPRs) MFMA A/B frag
typedef __attribute__((ext_vector_type(4))) float floatx4;    // MFMA C/D frag

// workspace layout, element offsets (4-byte units)
#define OFF_Q       0u           // scan scratch (pre-qkv) -> q fp32 [50000x128]
#define OFF_KV      6400000u     // kv packed bf16 pairs [50000x128] (k lo16, v hi16)
#define OFF_HHI     12800000u    // hupd_hi bf16 [50000x128]
#define OFF_HLO     16000000u    // hupd_lo bf16 [50000x128]
#define OFF_DISP    19200000u    // 150,000 floats
#define OFF_CNT     19350016u    // 50,000 ints
#define OFF_ROWPTR  19400032u    // 50,001 ints
#define OFF_CURSOR  19450048u    // 50,000 ints
#define OFF_ESD     19500064u    // 1,000,000 ints (int2 per edge: dst, dist^2 bits, CSR order)
#define OFF_WSPLIT  20500064u    // W{q,k,v,o,g1} split-bf16 frag order: 81,920 float slots
// end: 20,581,984 floats = 82.3 MB

static __device__ __forceinline__ unsigned short f2bf(float f) {
    unsigned u = __builtin_bit_cast(unsigned, f);
    unsigned r = (u + 0x7FFFu + ((u >> 16) & 1u)) >> 16;      // RNE
    return (unsigned short)r;
}
static __device__ __forceinline__ float bf2f(unsigned short s) {
    return __builtin_bit_cast(float, (unsigned)s << 16);
}

// prep: blocks [0,320) repack W{q,k,v,o,g1} into split-bf16 MFMA B-frag order;
// blocks [320,516) zero the degree counters.
__global__ void k_prep(const float* __restrict__ Wq, const float* __restrict__ Wk,
                       const float* __restrict__ Wv, const float* __restrict__ Wo,
                       const float* __restrict__ Wg1, unsigned short* __restrict__ ws,
                       int* __restrict__ cnt) {
    if (blockIdx.x >= SPLITW_BLOCKS) {
        int i = (blockIdx.x - SPLITW_BLOCKS) * 256 + threadIdx.x;
        if (i < N_NODES) cnt[i] = 0;
        return;
    }
    int t = blockIdx.x * 256 + threadIdx.x;          // exact: 5*16384
    int m = t >> 14, r = t & 16383;
    int k = r >> 7, n = r & 127;
    const float* W = (m == 0) ? Wq : (m == 1) ? Wk : (m == 2) ? Wv : (m == 3) ? Wo : Wg1;
    float x = W[k * 128 + n];
    int kc = k >> 5, kin = k & 31, quad = kin >> 3, j = kin & 7;
    int ct = n >> 4, nin = n & 15, lane = quad * 16 + nin;
    unsigned base = ((((unsigned)(m * 4 + kc) * 8 + ct) * 2) * 64 + lane) * 8 + j;
    unsigned short a = f2bf(x);
    ws[base] = a;                                    // hilo=0
    ws[base + 512] = f2bf(x - bf2f(a));              // hilo=1 (+64 lanes*8)
}

// degree histogram
__global__ void k_count(const int* __restrict__ src, int* __restrict__ cnt) {
    int e = blockIdx.x * 256 + threadIdx.x;
    if (e < N_EDGES) atomicAdd(&cnt[src[e]], 1);
}

// hierarchical scan over 50000 counts: per-block inclusive scan + block sums
__global__ __launch_bounds__(1024) void k_scan1(const int* __restrict__ cnt,
                                                int* __restrict__ loc,
                                                int* __restrict__ bsum, int n) {
    __shared__ int buf[1024];
    int t = threadIdx.x;
    int i = blockIdx.x * 1024 + t;
    int val = (i < n) ? cnt[i] : 0;
    buf[t] = val;
    __syncthreads();
    for (int off = 1; off < 1024; off <<= 1) {
        int a = (t >= off) ? buf[t - off] : 0;
        __syncthreads();
        buf[t] += a;
        __syncthreads();
    }
    if (i < n) loc[i] = buf[t];
    if (t == 1023) bsum[blockIdx.x] = buf[1023];
}

// scan2+scan3 fused: each block wave-scans the <=64 block sums locally,
// then produces rowptr (inclusive, shifted) and cursor (exclusive).
__global__ __launch_bounds__(256) void k_scan23(const int* __restrict__ cnt,
                                                const int* __restrict__ loc,
                                                const int* __restrict__ bsum,
                                                int* __restrict__ rowptr,
                                                int* __restrict__ cursor, int n, int nb) {
    __shared__ int sb[64];
    int t = threadIdx.x;
    if (t < 64) {
        int v = (t < nb) ? bsum[t] : 0;
        for (int off = 1; off < 64; off <<= 1) {
            int a = __shfl_up(v, off);
            if (t >= off) v += a;
        }
        sb[t] = v;                                   // inclusive scan of block sums
    }
    __syncthreads();
    int i = blockIdx.x * 256 + t;
    if (i < n) {
        int off = (i >= 1024) ? sb[(i >> 10) - 1] : 0;
        int incl = loc[i] + off;
        rowptr[i + 1] = incl;
        cursor[i] = incl - cnt[i];
    }
    if (i == 0) rowptr[0] = 0;
}

// FUSED qkv + scatter: blocks [0,1563) compute q/k/v via split-bf16 MFMA
// (h hi/lo split in-register); blocks [1563,3517) scatter (dst,dist^2) into
// CSR order. Independent work overlapped in one launch — scatter's random
// stores hide under qkv's memory-bound execution.
__global__ __launch_bounds__(256) void k_qkv_scatter(
    const float* __restrict__ h, const unsigned short* __restrict__ wsp,
    const float* __restrict__ bq, const float* __restrict__ bk, const float* __restrict__ bv,
    float* __restrict__ q, unsigned* __restrict__ kvp,
    const int* __restrict__ src, const int* __restrict__ dst,
    const float* __restrict__ dist, int* __restrict__ cursor, int2* __restrict__ esd) {
    if (blockIdx.x >= QKV_BLOCKS) {
        int e = (blockIdx.x - QKV_BLOCKS) * 256 + threadIdx.x;
        if (e < N_EDGES) {
            int pos = atomicAdd(&cursor[src[e]], 1);
            float dd = dist[e];
            esd[pos] = make_int2(dst[e], __float_as_int(dd * dd));
        }
        return;
    }

    const int wave = threadIdx.x >> 6, lane = threadIdx.x & 63;
    const int quad = lane >> 4, l15 = lane & 15;
    const int ct0 = wave * 2;
    const int row0 = blockIdx.x * 32;

    floatx4 acc[3][2][2];                            // [mat][ctl][rt]
#pragma unroll
    for (int m = 0; m < 3; ++m)
#pragma unroll
        for (int c = 0; c < 2; ++c)
#pragma unroll
            for (int r = 0; r < 2; ++r) acc[m][c][r] = (floatx4){0.f, 0.f, 0.f, 0.f};

#pragma unroll
    for (int kc = 0; kc < 4; ++kc) {
        short8 ah[2], al[2];
#pragma unroll
        for (int rt = 0; rt < 2; ++rt) {
            int row = row0 + rt * 16 + l15;
            if (row >= N_NODES) row = N_NODES - 1;
            const float* hp = h + (size_t)row * 128 + kc * 32 + quad * 8;
            float4 f0 = *(const float4*)(hp);
            float4 f1 = *(const float4*)(hp + 4);
            float fv[8] = {f0.x, f0.y, f0.z, f0.w, f1.x, f1.y, f1.z, f1.w};
#pragma unroll
            for (int j = 0; j < 8; ++j) {
                unsigned short hi = f2bf(fv[j]);
                ah[rt][j] = (short)hi;
                al[rt][j] = (short)f2bf(fv[j] - bf2f(hi));
            }
        }
#pragma unroll
        for (int m = 0; m < 3; ++m) {
#pragma unroll
            for (int ctl = 0; ctl < 2; ++ctl) {
                unsigned fb = ((((unsigned)(m * 4 + kc) * 8 + (ct0 + ctl)) * 2) * 64 + lane) * 8;
                short8 bh = *(const short8*)(wsp + fb);
                short8 bl = *(const short8*)(wsp + fb + 512);
#pragma unroll
                for (int rt = 0; rt < 2; ++rt) {
                    acc[m][ctl][rt] = __builtin_amdgcn_mfma_f32_16x16x32_bf16(
                        ah[rt], bh, acc[m][ctl][rt], 0, 0, 0);
                    acc[m][ctl][rt] = __builtin_amdgcn_mfma_f32_16x16x32_bf16(
                        ah[rt], bl, acc[m][ctl][rt], 0, 0, 0);
                    acc[m][ctl][rt] = __builtin_amdgcn_mfma_f32_16x16x32_bf16(
                        al[rt], bh, acc[m][ctl][rt], 0, 0, 0);
                }
            }
        }
    }

#pragma unroll
    for (int ctl = 0; ctl < 2; ++ctl) {
        int col = (ct0 + ctl) * 16 + l15;
        float bq_ = bq[col], bk_ = bk[col], bv_ = bv[col];
#pragma unroll
        for (int rt = 0; rt < 2; ++rt) {
#pragma unroll
            for (int reg = 0; reg < 4; ++reg) {
                int row = row0 + rt * 16 + quad * 4 + reg;
                if (row < N_NODES) {
                    q[(size_t)row * 128 + col] = acc[0][ctl][rt][reg] + bq_;
                    unsigned kb = f2bf(acc[1][ctl][rt][reg] + bk_);
                    unsigned vb = f2bf(acc[2][ctl][rt][reg] + bv_);
                    kvp[(size_t)row * 128 + col] = kb | (vb << 16);
                }
            }
        }
    }
}

// FUSED edge+node: one wave per node, 4-edge batched inner loop (proven
// config: VGPR 32, ~63% occupancy, ~3.3 TB/s).
__global__ __launch_bounds__(256) void k_edge_node(
    const float* __restrict__ q, const unsigned* __restrict__ kvp,
    const float* __restrict__ x,
    const int2* __restrict__ esd, const int* __restrict__ rowptr,
    const float* __restrict__ Wd, const float* __restrict__ bd,
    unsigned short* __restrict__ hupd_hi, unsigned short* __restrict__ hupd_lo,
    float* __restrict__ disp) {
    const int wave = threadIdx.x >> 6, lane = threadIdx.x & 63;
    const int node = blockIdx.x * 4 + wave;           // grid exact: N/4 blocks
    const int h = lane >> 3, sub = lane & 7;          // head, within-head slot
    const int beg = rowptr[node], end = rowptr[node + 1];

    const float2 qv = *(const float2*)(q + (size_t)node * 128 + 2 * lane);
    const float wdh = Wd[h], bdh = bd[h];
    const bool dal = (sub < 3);
    float xs = dal ? x[node * 3 + sub] : 0.f;
    const unsigned colo = 2 * lane;

    float acc0 = 0.f, acc1 = 0.f, s_own = 0.f, da = 0.f;

    for (int cb = beg; cb < end; cb += 64) {
        int idx = cb + lane;
        int dvec = 0; float d2vec = 0.f;
        if (idx < end) {
            int2 ed = esd[idx];
            dvec = ed.x;
            d2vec = __int_as_float(ed.y);
        }
        int clen = min(64, end - cb);
        int i = 0;
        for (; i + 4 <= clen; i += 4) {
            int di[4]; float dd2[4]; uint2 kv2[4]; float xg[4];
#pragma unroll
            for (int j = 0; j < 4; ++j) {
                di[j]  = __shfl(dvec, i + j);
                dd2[j] = __shfl(d2vec, i + j);
            }
#pragma unroll
            for (int j = 0; j < 4; ++j)
                kv2[j] = *(const uint2*)(kvp + (unsigned)di[j] * 128u + colo);
#pragma unroll
            for (int j = 0; j < 4; ++j)
                xg[j] = dal ? x[(unsigned)di[j] * 3u + sub] : 0.f;
#pragma unroll
            for (int j = 0; j < 4; ++j) {
                float k0 = __builtin_bit_cast(float, kv2[j].x << 16);
                float v0 = __builtin_bit_cast(float, kv2[j].x & 0xFFFF0000u);
                float k1 = __builtin_bit_cast(float, kv2[j].y << 16);
                float v1 = __builtin_bit_cast(float, kv2[j].y & 0xFFFF0000u);
                float p = qv.x * k0 + qv.y * k1;
                p += __shfl_xor(p, 1);
                p += __shfl_xor(p, 2);
                p += __shfl_xor(p, 4);                 // all 8 lanes of head h: full dot
                float w = __expf(p * 0.25f - (dd2[j] * wdh + bdh));
                s_own += w;
                acc0 += v0 * w;
                acc1 += v1 * w;
                da += (xg[j] - xs) * w;                // xs=xg=0 on non-da lanes
            }
        }
        for (; i < clen; ++i) {
            int dij  = __shfl(dvec, i);
            float d2 = __shfl(d2vec, i);
            uint2 kv2 = *(const uint2*)(kvp + (unsigned)dij * 128u + colo);
            float xgj = dal ? x[(unsigned)dij * 3u + sub] : 0.f;
            float k0 = __builtin_bit_cast(float, kv2.x << 16);
            float v0 = __builtin_bit_cast(float, kv2.x & 0xFFFF0000u);
            float k1 = __builtin_bit_cast(float, kv2.y << 16);
            float v1 = __builtin_bit_cast(float, kv2.y & 0xFFFF0000u);
            float p = qv.x * k0 + qv.y * k1;
            p += __shfl_xor(p, 1);
            p += __shfl_xor(p, 2);
            p += __shfl_xor(p, 4);
            float w = __expf(p * 0.25f - (d2 * wdh + bdh));
            s_own += w;
            acc0 += v0 * w;
            acc1 += v1 * w;
            da += (xgj - xs) * w;
        }
    }

    float inva = 1.f / fmaxf(s_own, 1e-9f);
    float o0 = acc0 * inva, o1 = acc1 * inva;
    unsigned short h0 = f2bf(o0), h1 = f2bf(o1);
    unsigned short l0 = f2bf(o0 - bf2f(h0)), l1 = f2bf(o1 - bf2f(h1));
    ((unsigned*)hupd_hi)[(size_t)node * 64 + lane] = (unsigned)h0 | ((unsigned)h1 << 16);
    ((unsigned*)hupd_lo)[(size_t)node * 64 + lane] = (unsigned)l0 | ((unsigned)l1 << 16);

    da *= 0.125f * inva;
    da += __shfl_xor(da, 8);
    da += __shfl_xor(da, 16);
    da += __shfl_xor(da, 32);
    if (lane < 3) disp[node * 3 + lane] = da;
}

// fused MFMA epilogue (proven geometry: block=256, 16 rows/wave):
// hout = h + hupd@Wo + bo (GEMM1); hout staged in per-wave padded LDS;
// GEMM2 = hout@Wg1; gate = tanh(sum silu(.)*Wg2); xout = x + gate*disp.
__global__ __launch_bounds__(256) void k_hout_gate(
    const float* __restrict__ h,
    const unsigned short* __restrict__ hupd_hi, const unsigned short* __restrict__ hupd_lo,
    const unsigned short* __restrict__ wsp,
    const float* __restrict__ bo, const float* __restrict__ bg1,
    const float* __restrict__ Wg2, const float* __restrict__ bg2,
    const float* __restrict__ x, const float* __restrict__ disp,
    float* __restrict__ hout, float* __restrict__ xout) {
    __shared__ float hb[4][16 * 132];                 // +4 dword pad per row
    const int wave = threadIdx.x >> 6, lane = threadIdx.x & 63;
    const int quad = lane >> 4, l15 = lane & 15;
    const int row0 = blockIdx.x * 64 + wave * 16;
    float* hbw = hb[wave];

    // ---- GEMM1: hupd @ Wo (m=3) ----
    floatx4 acc[8];
#pragma unroll
    for (int c = 0; c < 8; ++c) acc[c] = (floatx4){0.f, 0.f, 0.f, 0.f};
#pragma unroll
    for (int kc = 0; kc < 4; ++kc) {
        int row = row0 + l15;
        if (row >= N_NODES) row = N_NODES - 1;
        size_t aoff = (size_t)row * 128 + kc * 32 + quad * 8;
        short8 ah = *(const short8*)(hupd_hi + aoff);
        short8 al = *(const short8*)(hupd_lo + aoff);
#pragma unroll
        for (int ct = 0; ct < 8; ++ct) {
            unsigned fb = ((((unsigned)(3 * 4 + kc) * 8 + ct) * 2) * 64 + lane) * 8;
            short8 bh = *(const short8*)(wsp + fb);
            short8 bl = *(const short8*)(wsp + fb + 512);
            acc[ct] = __builtin_amdgcn_mfma_f32_16x16x32_bf16(ah, bh, acc[ct], 0, 0, 0);
            acc[ct] = __builtin_amdgcn_mfma_f32_16x16x32_bf16(ah, bl, acc[ct], 0, 0, 0);
            acc[ct] = __builtin_amdgcn_mfma_f32_16x16x32_bf16(al, bh, acc[ct], 0, 0, 0);
        }
    }

    // epilogue 1: add h + bo, write hout (global) + LDS tile
#pragma unroll
    for (int ct = 0; ct < 8; ++ct) {
        int col = ct * 16 + l15;
        float bias = bo[col];
#pragma unroll
        for (int reg = 0; reg < 4; ++reg) {
            int row = row0 + quad * 4 + reg;
            float val = acc[ct][reg] + bias;
            if (row < N_NODES) {
                val += h[(size_t)row * 128 + col];
                hout[(size_t)row * 128 + col] = val;
            }
            hbw[(quad * 4 + reg) * 132 + col] = val;
        }
    }
    __asm__ volatile("s_waitcnt lgkmcnt(0)" ::: "memory");

    // ---- GEMM2: hout @ Wg1 (m=4), A-frags read from LDS ----
    floatx4 acc2[8];
#pragma unroll
    for (int c = 0; c < 8; ++c) acc2[c] = (floatx4){0.f, 0.f, 0.f, 0.f};
#pragma unroll
    for (int kc = 0; kc < 4; ++kc) {
        const float* ap = hbw + l15 * 132 + kc * 32 + quad * 8;
        float4 f0 = *(const float4*)(ap);
        float4 f1 = *(const float4*)(ap + 4);
        float fv[8] = {f0.x, f0.y, f0.z, f0.w, f1.x, f1.y, f1.z, f1.w};
        short8 ah, al;
#pragma unroll
        for (int j = 0; j < 8; ++j) {
            unsigned short hi = f2bf(fv[j]);
            ah[j] = (short)hi;
            al[j] = (short)f2bf(fv[j] - bf2f(hi));
        }
#pragma unroll
        for (int ct = 0; ct < 8; ++ct) {
            unsigned fb = ((((unsigned)(4 * 4 + kc) * 8 + ct) * 2) * 64 + lane) * 8;
            short8 bh = *(const short8*)(wsp + fb);
            short8 bl = *(const short8*)(wsp + fb + 512);
            acc2[ct] = __builtin_amdgcn_mfma_f32_16x16x32_bf16(ah, bh, acc2[ct], 0, 0, 0);
            acc2[ct] = __builtin_amdgcn_mfma_f32_16x16x32_bf16(ah, bl, acc2[ct], 0, 0, 0);
            acc2[ct] = __builtin_amdgcn_mfma_f32_16x16x32_bf16(al, bh, acc2[ct], 0, 0, 0);
        }
    }

    // epilogue 2: silu * Wg2, reduce cols -> gate -> xout
    float pr[4] = {0.f, 0.f, 0.f, 0.f};
#pragma unroll
    for (int ct = 0; ct < 8; ++ct) {
        int col = ct * 16 + l15;
        float b1 = bg1[col];
        float w2 = Wg2[col];
#pragma unroll
        for (int reg = 0; reg < 4; ++reg) {
            float z = acc2[ct][reg] + b1;
            pr[reg] += (z / (1.f + __expf(-z))) * w2;
        }
    }
#pragma unroll
    for (int off = 1; off < 16; off <<= 1) {
#pragma unroll
        for (int reg = 0; reg < 4; ++reg) pr[reg] += __shfl_xor(pr[reg], off);
    }
    if (l15 == 0) {
        float b2 = bg2[0];
#pragma unroll
        for (int reg = 0; reg < 4; ++reg) {
            int row = row0 + quad * 4 + reg;
            if (row < N_NODES) {
                float g = tanhf(pr[reg] + b2);
#pragma unroll
                for (int dd = 0; dd < 3; ++dd) {
                    int oo = row * 3 + dd;
                    xout[oo] = x[oo] + g * disp[oo];
                }
            }
        }
    }
}

extern "C" void kernel_launch(void* const* d_in, const int* in_sizes, int n_in,
                              void* d_out, int out_size, void* d_ws, size_t ws_size,
                              hipStream_t stream) {
    const float* h    = (const float*)d_in[0];
    const float* x    = (const float*)d_in[1];
    const int*   src  = (const int*)d_in[2];
    const int*   dst  = (const int*)d_in[3];
    const float* dist = (const float*)d_in[4];
    const float* Wq = (const float*)d_in[5];  const float* bq = (const float*)d_in[6];
    const float* Wk = (const float*)d_in[7];  const float* bk = (const float*)d_in[8];
    const float* Wv = (const float*)d_in[9];  const float* bv = (const float*)d_in[10];
    const float* Wo = (const float*)d_in[11]; const float* bo = (const float*)d_in[12];
    const float* Wd = (const float*)d_in[13]; const float* bd = (const float*)d_in[14];
    const float* Wg1 = (const float*)d_in[15]; const float* bg1 = (const float*)d_in[16];
    const float* Wg2 = (const float*)d_in[17]; const float* bg2 = (const float*)d_in[18];

    float* ws    = (float*)d_ws;
    float* q     = ws + OFF_Q;
    unsigned* kvp = (unsigned*)(ws + OFF_KV);
    float* disp  = ws + OFF_DISP;
    int* cnt     = (int*)(ws + OFF_CNT);
    int* rowptr  = (int*)(ws + OFF_ROWPTR);
    int* cursor  = (int*)(ws + OFF_CURSOR);
    int2* esd    = (int2*)(ws + OFF_ESD);
    unsigned short* wsp = (unsigned short*)(ws + OFF_WSPLIT);
    // scan scratch in q region, consumed before k_qkv_scatter writes q
    int* loc    = (int*)(ws + OFF_Q);
    int* bsum   = (int*)(ws + OFF_Q + 500000u);
    unsigned short* hupd_hi = (unsigned short*)(ws + OFF_HHI);
    unsigned short* hupd_lo = (unsigned short*)(ws + OFF_HLO);
    float* hout = (float*)d_out;
    float* xout = hout + (size_t)N_NODES * HIDDEN;

    const int nscan = (N_NODES + 1023) / 1024;    // 49

    k_prep<<<SPLITW_BLOCKS + ZERO_BLOCKS, 256, 0, stream>>>(Wq, Wk, Wv, Wo, Wg1, wsp, cnt);
    k_count<<<SCAT_BLOCKS, 256, 0, stream>>>(src, cnt);
    k_scan1<<<nscan, 1024, 0, stream>>>(cnt, loc, bsum, N_NODES);
    k_scan23<<<ZERO_BLOCKS, 256, 0, stream>>>(cnt, loc, bsum, rowptr, cursor, N_NODES, nscan);
    k_qkv_scatter<<<QKV_BLOCKS + SCAT_BLOCKS, 256, 0, stream>>>(
        h, wsp, bq, bk, bv, q, kvp, src, dst, dist, cursor, esd);
    k_edge_node<<<N_NODES / 4, 256, 0, stream>>>(q, kvp, x, esd, rowptr,
                                                 Wd, bd, hupd_hi, hupd_lo, disp);
    k_hout_gate<<<(N_NODES + 63) / 64, 256, 0, stream>>>(h, hupd_hi, hupd_lo, wsp,
                                                         bo, bg1, Wg2, bg2,
                                                         x, disp, hout, xout);
}